// Round 22
// baseline (155.969 us; speedup 1.0000x reference)
//
#include <hip/hip_runtime.h>
#include <hip/hip_bf16.h>
#include <hip/hip_fp16.h>
#include <math.h>

// Problem constants
#define BB   8
#define CIN  256
#define HH   64
#define WW   64
#define OMC  27          // 3*K offset/mask channels
#define HW   (HH*WW)
#define KTOT (CIN*9)     // 2304 GEMM K
#define NPIX 32          // pixels per block (deform N tile)
#define SPITCH 296       // LDS sample row pitch in halves (288 + 8 pad)
#define XP1    40        // om x-tile ch pitch (halves)
#define TPW    18        // deform tile words per rc entry (16 used + 2 pad, EVEN
                         // -> b64-aligned 4-channel corner reads)

typedef short bf16x8 __attribute__((ext_vector_type(8)));
typedef float f32x4  __attribute__((ext_vector_type(4)));

__device__ __forceinline__ unsigned short f2bf(float f) {
    union { float f; unsigned int u; } v; v.f = f;
    unsigned int r = v.u + 0x7FFFu + ((v.u >> 16) & 1u);   // RNE
    return (unsigned short)(r >> 16);
}
__device__ __forceinline__ unsigned int pk2bf(float a, float b) {
    // v_cvt_pk_bf16_f32: 1 instr, RNE, a in low half (same as f2bf pair)
    union { __hip_bfloat162 h; unsigned int u; } c;
    c.h = __float22bfloat162_rn(make_float2(a, b));
    return c.u;
}
__device__ __forceinline__ float bflo(unsigned int a) {
    union { unsigned int u; float f; } c; c.u = a << 16; return c.f;
}
__device__ __forceinline__ float bfhi(unsigned int a) {
    union { unsigned int u; float f; } c; c.u = a & 0xFFFF0000u; return c.f;
}

// ---------------------------------------------------------------------------
// Kernel 0 (merged prep): blocks [0,2304) convert w_dc -> wA (tap-major
// chunk-local k' = (c>>5)*288 + tap*32 + (c&31); wA[k'>>3][o][k'&7]);
// blocks [2304,2592) convert w_om -> wOmA (padded/swizzled, o<32pad).
// ---------------------------------------------------------------------------
__global__ __launch_bounds__(256) void prep_kernel(
    const float* __restrict__ w_dc, const float* __restrict__ w_om,
    unsigned short* __restrict__ wA, unsigned short* __restrict__ wOmA)
{
    int bid = blockIdx.x;
    if (bid < 2304) {
        int e = bid * 256 + threadIdx.x;         // 256*2304 elements
        int o = e / KTOT;
        int k = e - o * KTOT;
        int c   = k / 9;
        int tap = k - c * 9;
        int kp  = (c >> 5) * 288 + tap * 32 + (c & 31);
        wA[((size_t)(kp >> 3) * 256 + o) * 8 + (kp & 7)] = f2bf(w_dc[e]);
    } else {
        int e = (bid - 2304) * 256 + threadIdx.x;  // 73728
        int j  = e & 7;
        int t1 = e >> 3;
        int o  = t1 & 31;
        int t2 = t1 >> 5;
        int cb = t2 & 3;
        int t3 = t2 >> 2;
        int cc = t3 & 7;
        int tap = t3 >> 3;
        int c = cc * 32 + cb * 8 + j;
        float v = (o < OMC) ? w_om[(size_t)o * KTOT + c * 9 + tap] : 0.f;
        wOmA[e] = f2bf(v);
    }
}

// ---------------------------------------------------------------------------
// Kernel A: om-conv MFMA, grid 1024 = (b, h, w-half), 512 thr (8 waves).
// K split across wave-groups: waves 0-3 chunks 0-3, waves 4-7 chunks 4-7;
// group 1 deposits partial in LDS, group 0 adds + bias + stores. LDS 32.6KB
// -> 4 blocks/CU. (R21 verified.)
// ---------------------------------------------------------------------------
__global__ __launch_bounds__(512, 4) void om_mfma_kernel(
    const float* __restrict__ x, const unsigned short* __restrict__ wOmA,
    const float* __restrict__ b_om, float* __restrict__ om)
{
    const int rawb = blockIdx.x;
    const int obid = ((rawb & 7) << 7) | (rawb >> 3);   // batch-per-XCD swizzle
    const int b    = obid >> 7;
    const int h    = (obid >> 1) & 63;
    const int w0   = (obid & 1) * 32;
    const int t    = threadIdx.x;
    const int wv   = t >> 6;             // wave 0..7
    const int grp  = wv >> 2;            // K-group: chunks grp*4 .. grp*4+3
    const int tg   = t & 255;            // thread id within group
    const int lane = t & 63;
    const int lq   = lane >> 4;
    const int lm   = lane & 15;
    const int wg   = wv & 3;             // wave within group
    const int mfp  = (wg >> 1) & 1;      // M-frag (o block of 16)
    const int nfp  = wg & 1;             // N-frag (pixel block of 16)
    const int p    = nfp * 16 + lm;      // pixel 0..31

    __shared__ __align__(16) unsigned short sX[4 * 102 * XP1]; // 32640 B: 2 dbufs
    float* som_tmp = reinterpret_cast<float*>(sX);             // 864 fl overlay

    unsigned short* bufA = sX + grp * 2 * (102 * XP1);
    unsigned short* bufB = bufA + 102 * XP1;

    const size_t xb_base = (size_t)b * CIN * HW;
    const float* gx_base = x + xb_base;
    const bf16x8* wOmV = reinterpret_cast<const bf16x8*>(wOmA);

    f32x4 accOm = (f32x4)(0.f);

    // group-local staging: 256 threads stage 3264 els (13/thread)
    auto stage1g = [&](int cc, unsigned short* dst) {
        const float* gch = gx_base + (size_t)cc * 32 * HW;
#pragma unroll
        for (int i = 0; i < 13; ++i) {
            int e = tg + i * 256;
            if (e < 102 * 32) {
                int cl  = e / 102;
                int rc  = e - cl * 102;
                int row = rc / 34;
                int col = rc - row * 34;
                int gy  = h - 1 + row;
                int gxx = w0 - 1 + col;
                float v = 0.f;
                if (gy >= 0 && gy < HH && (unsigned)gxx < WW)
                    v = gch[cl * HW + gy * WW + gxx];
                dst[rc * XP1 + cl] = f2bf(v);
            }
        }
    };

    stage1g(grp * 4, bufA);
    __syncthreads();
    for (int q = 0; q < 4; ++q) {
        const int ch = grp * 4 + q;
        unsigned short* cur = (q & 1) ? bufB : bufA;
        unsigned short* nxt = (q & 1) ? bufA : bufB;
        if (q < 3) stage1g(ch + 1, nxt);     // loads issue early, hide under MFMA
#pragma unroll
        for (int tap = 0; tap < 9; ++tap) {
            int th = tap / 3, tw = tap % 3;
            bf16x8 bfr = *reinterpret_cast<const bf16x8*>(
                &cur[(th * 34 + p + tw) * XP1 + lq * 8]);
            bf16x8 af = wOmV[(((tap * 8 + ch) * 4 + lq) * 32) + mfp * 16 + lm];
            accOm = __builtin_amdgcn_mfma_f32_16x16x32_bf16(af, bfr, accOm, 0, 0, 0);
        }
        __syncthreads();
    }

    // group 1 deposits its partial (each (o,p) written exactly once)
    if (grp == 1) {
#pragma unroll
        for (int r = 0; r < 4; ++r) {
            int o = mfp * 16 + lq * 4 + r;
            if (o < 32)
                som_tmp[o * 32 + p] = accOm[r];
        }
    }
    __syncthreads();
    if (grp == 0) {
#pragma unroll
        for (int r = 0; r < 4; ++r) {
            int o = mfp * 16 + lq * 4 + r;
            if (o < OMC)
                om[((size_t)(b * OMC + o) * HH + h) * WW + w0 + p] =
                    accOm[r] + som_tmp[o * 32 + p] + b_om[o];
        }
    }
}

// ---------------------------------------------------------------------------
// Kernel B: deform gather + bf16 MFMA GEMM. 512 thr (8 waves), M=256, N=32.
// THIS ROUND: tile pitch 17->18 words (even) -> b64-aligned corner reads of
// 4 channels; gather thread = (pix, ch-quad sp, tap-parity th); corner
// offsets CONDITIONAL (dxw=dtx*18, dyw=dty*720) so weight-0 corners re-read
// base -> no guard region, tile 14.4KB, LDS 37.9KB -> 4 blocks/CU.
// Gather LDS wave-instrs per chunk ~54 -> ~27 (LDS pipe was ~60% of dur).
// XCD swizzle: obid=((raw&7)<<7)|(raw>>3) -> batch b on XCD b.
// ---------------------------------------------------------------------------
__global__ __launch_bounds__(512, 4) void deform_mfma_kernel(
    const float* __restrict__ x, const float* __restrict__ om,
    const unsigned short* __restrict__ wA, const float* __restrict__ b_dc,
    float* __restrict__ out)
{
    const int rawb = blockIdx.x;
    const int obid = ((rawb & 7) << 7) | (rawb >> 3);   // batch-per-XCD swizzle
    const int b    = obid >> 7;
    const int h    = (obid >> 1) & 63;
    const int w0   = (obid & 1) * NPIX;
    const int t    = threadIdx.x;
    const int wv   = t >> 6;             // wave 0..7
    const int lane = t & 63;
    const int lq   = lane >> 4;          // k-quarter
    const int lm   = lane & 15;

    __shared__ __align__(16) unsigned short sS[NPIX * SPITCH]; // 18944 B
    __shared__ __align__(16) unsigned short sR[7200];          // 14400 B tile
    __shared__ __align__(16) int4 s_par[9 * NPIX];             // 4608 B params

    const size_t xb_base = (size_t)b * CIN * HW;
    const float* gx_base = x + xb_base;

    // ---- staging precompute: entry n = t+i*512 over 3200 (rc,slot) ----
    // packed: lword(12b) | slot(4b)<<12 | goff(12b)<<16 ; -1 = inactive
    int stg[7];
#pragma unroll
    for (int i = 0; i < 7; ++i) {
        int n = t + i * 512;
        if (n < 3200) {
            int slot = n / 200;              // 0..15 (channel pair)
            int rc   = n - slot * 200;       // 0..199 (r*40+c)
            int r    = rc / 40;
            int c    = rc - r * 40;
            int gy   = min(max(h - 2 + r, 0), HH - 1);
            int gx   = min(max(w0 - 4 + c, 0), WW - 1);
            stg[i] = (rc * TPW + slot) | (slot << 12) | ((gy * WW + gx) << 16);
        } else stg[i] = -1;
    }

    unsigned int* tWw = reinterpret_cast<unsigned int*>(sR);
    const unsigned int* tW = tWw;

    // ---- prologue: issue chunk-0 staging loads, params, write tile ----
    float L0[7], L1[7];
    {
        const float* gch = gx_base;
#pragma unroll
        for (int i = 0; i < 7; ++i)
            if (stg[i] >= 0) {
                int sl = (stg[i] >> 12) & 0xF;
                int go = (stg[i] >> 16) & 0xFFF;
                L0[i] = gch[(size_t)(2 * sl) * HW + go];
                L1[i] = gch[(size_t)(2 * sl + 1) * HW + go];
            }
    }

    if (t < 9 * NPIX) {
        int tap = t >> 5;
        int pix = t & 31;
        const float* omb = om + ((size_t)b * OMC * HH + h) * WW + w0 + pix;
        float dy = omb[(size_t)(2 * tap) * HW];
        float dx = omb[(size_t)(2 * tap + 1) * HW];
        float mv = omb[(size_t)(18 + tap) * HW];
        float m  = 1.f / (1.f + expf(-mv));
        float py = (float)(h - 1 + tap / 3) + dy;
        float px = (float)(w0 + pix - 1 + tap % 3) + dx;
        float y0f = floorf(py), x0f = floorf(px);
        float wy1 = py - y0f, wx1 = px - x0f;
        float wy0 = 1.f - wy1, wx0 = 1.f - wx1;
        int y0 = (int)y0f, x0 = (int)x0f;
        int y1 = y0 + 1, x1 = x0 + 1;
        bool yv0 = (y0 >= 0) && (y0 < HH);
        bool yv1 = (y1 >= 0) && (y1 < HH);
        bool xv0 = (x0 >= 0) && (x0 < WW);
        bool xv1 = (x1 >= 0) && (x1 < WW);
        int yc0 = min(max(y0, 0), HH - 1), yc1 = min(max(y1, 0), HH - 1);
        int xc0 = min(max(x0, 0), WW - 1), xc1 = min(max(x1, 0), WW - 1);
        float wwx = (yv0 && xv0) ? wy0 * wx0 * m : 0.f;
        float wwy = (yv0 && xv1) ? wy0 * wx1 * m : 0.f;
        float wwz = (yv1 && xv0) ? wy1 * wx0 * m : 0.f;
        float www = (yv1 && xv1) ? wy1 * wx1 * m : 0.f;
        // fold clamp-duplicate corners into weights (exact: duplicated coord)
        if (xc1 == xc0) { wwx += wwy; wwy = 0.f; wwz += www; www = 0.f; }
        if (yc1 == yc0) { wwx += wwz; wwz = 0.f; wwy += www; www = 0.f; }
        bool inT = (yc0 >= h - 2) && (yc1 <= h + 2) &&
                   (xc0 >= w0 - 4) && (xc1 <= w0 + 35);
        int lb = (yc0 - (h - 2)) * 40 + (xc0 - (w0 - 4));
        int pk = (lb & 0xFF) | ((xc1 - xc0) << 8) | ((yc1 - yc0) << 9)
               | ((yc0 * WW + xc0) << 10);
        if (!inT) pk |= (int)0x80000000;
        __half2 wab = __floats2half2_rn(wwx, wwy);
        __half2 wcd = __floats2half2_rn(wwz, www);
        s_par[t] = make_int4(pk,
                             *reinterpret_cast<int*>(&wab),
                             *reinterpret_cast<int*>(&wcd), 0);
    }
    {   // write chunk-0 tile (waits staged loads)
#pragma unroll
        for (int i = 0; i < 7; ++i)
            if (stg[i] >= 0)
                tWw[stg[i] & 0xFFF] = pk2bf(L0[i], L1[i]);
    }
    __syncthreads();           // params + chunk-0 tile ready

    // ================= main deform GEMM =================
    f32x4 acc[2][2];
#pragma unroll
    for (int i = 0; i < 2; ++i)
#pragma unroll
        for (int j = 0; j < 2; ++j)
            acc[i][j] = (f32x4)(0.f);

    const int pix = t >> 4;              // 0..31 gather pixel
    const int sp  = (t >> 1) & 7;        // channel quad: ch 4sp..4sp+3
    const int th  = t & 1;               // tap parity

    for (int ch = 0; ch < 8; ++ch) {
        // ---- gather: per tap 1 b128 param + 4 b64 corners (4 channels) ----
#pragma unroll
        for (int tap = th; tap < 9; tap += 2) {
            int idx = tap * NPIX + pix;
            int4 pv = s_par[idx];
            int pk  = pv.x;
            float2 wab = __half22float2(*reinterpret_cast<__half2*>(&pv.y));
            float2 wcd = __half22float2(*reinterpret_cast<__half2*>(&pv.z));
            float v0, v1, v2, v3;
            if (pk >= 0) {
                int base = (pk & 0xFF) * TPW + 2 * sp;
                int dxw  = ((pk >> 8) & 1) * TPW;
                int dyw  = ((pk >> 9) & 1) * (40 * TPW);
                uint2 a00 = *reinterpret_cast<const uint2*>(&tW[base]);
                uint2 a01 = *reinterpret_cast<const uint2*>(&tW[base + dxw]);
                uint2 a10 = *reinterpret_cast<const uint2*>(&tW[base + dyw]);
                uint2 a11 = *reinterpret_cast<const uint2*>(&tW[base + dyw + dxw]);
                v0 = wab.x * bflo(a00.x) + wab.y * bflo(a01.x)
                   + wcd.x * bflo(a10.x) + wcd.y * bflo(a11.x);
                v1 = wab.x * bfhi(a00.x) + wab.y * bfhi(a01.x)
                   + wcd.x * bfhi(a10.x) + wcd.y * bfhi(a11.x);
                v2 = wab.x * bflo(a00.y) + wab.y * bflo(a01.y)
                   + wcd.x * bflo(a10.y) + wcd.y * bflo(a11.y);
                v3 = wab.x * bfhi(a00.y) + wab.y * bfhi(a01.y)
                   + wcd.x * bfhi(a10.y) + wcd.y * bfhi(a11.y);
            } else {
                int off00 = (pk >> 10) & 0xFFF;
                int d01 = (pk >> 8) & 1;
                int d10 = ((pk >> 9) & 1) * WW;
                const float* xc = x + xb_base + (size_t)(ch * 32 + 4 * sp) * HW;
                float vv[4];
#pragma unroll
                for (int j = 0; j < 4; ++j) {
                    vv[j] = wab.x * xc[off00]       + wab.y * xc[off00 + d01]
                          + wcd.x * xc[off00 + d10] + wcd.y * xc[off00 + d10 + d01];
                    xc += HW;
                }
                v0 = vv[0]; v1 = vv[1]; v2 = vv[2]; v3 = vv[3];
            }
            *reinterpret_cast<uint2*>(&sS[pix * SPITCH + tap * 32 + 4 * sp]) =
                make_uint2(pk2bf(v0, v1), pk2bf(v2, v3));
        }
        __syncthreads();                  // sS ready; tile consumed

        // ---- issue next chunk's staging loads (hide under MFMA) ----
        if (ch < 7) {
            const float* gch = gx_base + (size_t)(ch + 1) * 32 * HW;
#pragma unroll
            for (int i = 0; i < 7; ++i)
                if (stg[i] >= 0) {
                    int sl = (stg[i] >> 12) & 0xF;
                    int go = (stg[i] >> 16) & 0xFFF;
                    L0[i] = gch[(size_t)(2 * sl) * HW + go];
                    L1[i] = gch[(size_t)(2 * sl + 1) * HW + go];
                }
        }

        // ---- MFMA: wave wv computes o in [wv*32, wv*32+32) ----
        const int kb_base = ch * 36;
        const bf16x8* wAv = reinterpret_cast<const bf16x8*>(wA);
#pragma unroll 1
        for (int ks = 0; ks < 9; ++ks) {
            bf16x8 bfr[2];
#pragma unroll
            for (int nf = 0; nf < 2; ++nf)
                bfr[nf] = *reinterpret_cast<const bf16x8*>(
                    &sS[(nf * 16 + lm) * SPITCH + ks * 32 + lq * 8]);
#pragma unroll
            for (int mf = 0; mf < 2; ++mf) {
                int o  = wv * 32 + mf * 16 + lm;
                int kb = kb_base + ks * 4 + lq;
                bf16x8 af = wAv[(size_t)kb * 256 + o];
#pragma unroll
                for (int nf = 0; nf < 2; ++nf)
                    acc[mf][nf] = __builtin_amdgcn_mfma_f32_16x16x32_bf16(
                        af, bfr[nf], acc[mf][nf], 0, 0, 0);
            }
        }

        // ---- write next tile (loads have landed under MFMA) ----
        if (ch < 7) {
#pragma unroll
            for (int i = 0; i < 7; ++i)
                if (stg[i] >= 0)
                    tWw[stg[i] & 0xFFF] = pk2bf(L0[i], L1[i]);
        }
        __syncthreads();        // sS free + next tile ready
    }

    // ---- epilogue: D row = lq*4 + r, col = lm ----
#pragma unroll
    for (int mf = 0; mf < 2; ++mf) {
#pragma unroll
        for (int r = 0; r < 4; ++r) {
            int o = wv * 32 + mf * 16 + lq * 4 + r;
            float bo = b_dc[o];
#pragma unroll
            for (int nf = 0; nf < 2; ++nf) {
                int p = nf * 16 + lm;
                out[((size_t)(b * 256 + o)) * HW + h * WW + w0 + p] = acc[mf][nf][r] + bo;
            }
        }
    }
}

extern "C" void kernel_launch(void* const* d_in, const int* in_sizes, int n_in,
                              void* d_out, int out_size, void* d_ws, size_t ws_size,
                              hipStream_t stream) {
    const float* x    = (const float*)d_in[0];
    const float* w_om = (const float*)d_in[1];
    const float* b_om = (const float*)d_in[2];
    const float* w_dc = (const float*)d_in[3];
    const float* b_dc = (const float*)d_in[4];
    float* out = (float*)d_out;

    unsigned short* wA   = (unsigned short*)d_ws;                    // 1,179,648 B
    unsigned short* wOmA = (unsigned short*)((char*)d_ws + 1179648); //   147,456 B
    float*          om   = (float*)((char*)d_ws + 1327104);          // 3,538,944 B

    prep_kernel<<<2304 + 288, 256, 0, stream>>>(w_dc, w_om, wA, wOmA);
    om_mfma_kernel<<<BB * HH * 2, 512, 0, stream>>>(x, wOmA, b_om, om);
    deform_mfma_kernel<<<BB * HH * 2, 512, 0, stream>>>(x, om, wA, b_dc, out);
}

// Round 23
// 149.825 us; speedup vs baseline: 1.0410x; 1.0410x over previous
//
#include <hip/hip_runtime.h>
#include <hip/hip_bf16.h>
#include <hip/hip_fp16.h>
#include <math.h>

// Problem constants
#define BB   8
#define CIN  256
#define HH   64
#define WW   64
#define OMC  27          // 3*K offset/mask channels
#define HW   (HH*WW)
#define KTOT (CIN*9)     // 2304 GEMM K
#define NPIX 32          // pixels per block (deform N tile)
#define SPITCH 296       // LDS sample row pitch in halves (288 + 8 pad)
#define XP1    40        // om x-tile ch pitch (halves)
#define TPW    17        // deform tile words per rc entry (32ch bf16 + 1 pad)

typedef short bf16x8 __attribute__((ext_vector_type(8)));
typedef float f32x4  __attribute__((ext_vector_type(4)));

__device__ __forceinline__ unsigned short f2bf(float f) {
    union { float f; unsigned int u; } v; v.f = f;
    unsigned int r = v.u + 0x7FFFu + ((v.u >> 16) & 1u);   // RNE
    return (unsigned short)(r >> 16);
}
__device__ __forceinline__ unsigned int pk2bf(float a, float b) {
    // v_cvt_pk_bf16_f32: 1 instr, RNE, a in low half (same as f2bf pair)
    union { __hip_bfloat162 h; unsigned int u; } c;
    c.h = __float22bfloat162_rn(make_float2(a, b));
    return c.u;
}
__device__ __forceinline__ float bflo(unsigned int a) {
    union { unsigned int u; float f; } c; c.u = a << 16; return c.f;
}
__device__ __forceinline__ float bfhi(unsigned int a) {
    union { unsigned int u; float f; } c; c.u = a & 0xFFFF0000u; return c.f;
}

// ---------------------------------------------------------------------------
// Kernel 0 (merged prep): blocks [0,2304) convert w_dc -> wA (tap-major
// chunk-local k' = (c>>5)*288 + tap*32 + (c&31); wA[k'>>3][o][k'&7]);
// blocks [2304,2592) convert w_om -> wOmA (padded/swizzled, o<32pad).
// ---------------------------------------------------------------------------
__global__ __launch_bounds__(256) void prep_kernel(
    const float* __restrict__ w_dc, const float* __restrict__ w_om,
    unsigned short* __restrict__ wA, unsigned short* __restrict__ wOmA)
{
    int bid = blockIdx.x;
    if (bid < 2304) {
        int e = bid * 256 + threadIdx.x;         // 256*2304 elements
        int o = e / KTOT;
        int k = e - o * KTOT;
        int c   = k / 9;
        int tap = k - c * 9;
        int kp  = (c >> 5) * 288 + tap * 32 + (c & 31);
        wA[((size_t)(kp >> 3) * 256 + o) * 8 + (kp & 7)] = f2bf(w_dc[e]);
    } else {
        int e = (bid - 2304) * 256 + threadIdx.x;  // 73728
        int j  = e & 7;
        int t1 = e >> 3;
        int o  = t1 & 31;
        int t2 = t1 >> 5;
        int cb = t2 & 3;
        int t3 = t2 >> 2;
        int cc = t3 & 7;
        int tap = t3 >> 3;
        int c = cc * 32 + cb * 8 + j;
        float v = (o < OMC) ? w_om[(size_t)o * KTOT + c * 9 + tap] : 0.f;
        wOmA[e] = f2bf(v);
    }
}

// ---------------------------------------------------------------------------
// Kernel A: om-conv MFMA, grid 1024 = (b, h, w-half), 512 thr (8 waves).
// K SPLIT ACROSS WAVE-GROUPS: waves 0-3 accumulate chunks 0-3, waves 4-7
// chunks 4-7. Each group stages its own dbuf tile (256 thr, 13 els/thr).
// Group 1's partial deposited in LDS; group 0 adds + bias + stores.
// LDS 32.6KB -> 4 blocks/CU. (R21-verified: total 150.0us.)
// ---------------------------------------------------------------------------
__global__ __launch_bounds__(512, 4) void om_mfma_kernel(
    const float* __restrict__ x, const unsigned short* __restrict__ wOmA,
    const float* __restrict__ b_om, float* __restrict__ om)
{
    const int rawb = blockIdx.x;
    const int obid = ((rawb & 7) << 7) | (rawb >> 3);   // batch-per-XCD swizzle
    const int b    = obid >> 7;
    const int h    = (obid >> 1) & 63;
    const int w0   = (obid & 1) * 32;
    const int t    = threadIdx.x;
    const int wv   = t >> 6;             // wave 0..7
    const int grp  = wv >> 2;            // K-group: chunks grp*4 .. grp*4+3
    const int tg   = t & 255;            // thread id within group
    const int lane = t & 63;
    const int lq   = lane >> 4;
    const int lm   = lane & 15;
    const int wg   = wv & 3;             // wave within group
    const int mfp  = (wg >> 1) & 1;      // M-frag (o block of 16)
    const int nfp  = wg & 1;             // N-frag (pixel block of 16)
    const int p    = nfp * 16 + lm;      // pixel 0..31

    __shared__ __align__(16) unsigned short sX[4 * 102 * XP1]; // 32640 B: 2 dbufs
    float* som_tmp = reinterpret_cast<float*>(sX);             // 864 fl overlay

    unsigned short* bufA = sX + grp * 2 * (102 * XP1);
    unsigned short* bufB = bufA + 102 * XP1;

    const size_t xb_base = (size_t)b * CIN * HW;
    const float* gx_base = x + xb_base;
    const bf16x8* wOmV = reinterpret_cast<const bf16x8*>(wOmA);

    f32x4 accOm = (f32x4)(0.f);

    // group-local staging: 256 threads stage 3264 els (13/thread)
    auto stage1g = [&](int cc, unsigned short* dst) {
        const float* gch = gx_base + (size_t)cc * 32 * HW;
#pragma unroll
        for (int i = 0; i < 13; ++i) {
            int e = tg + i * 256;
            if (e < 102 * 32) {
                int cl  = e / 102;
                int rc  = e - cl * 102;
                int row = rc / 34;
                int col = rc - row * 34;
                int gy  = h - 1 + row;
                int gxx = w0 - 1 + col;
                float v = 0.f;
                if (gy >= 0 && gy < HH && (unsigned)gxx < WW)
                    v = gch[cl * HW + gy * WW + gxx];
                dst[rc * XP1 + cl] = f2bf(v);
            }
        }
    };

    stage1g(grp * 4, bufA);
    __syncthreads();
    for (int q = 0; q < 4; ++q) {
        const int ch = grp * 4 + q;
        unsigned short* cur = (q & 1) ? bufB : bufA;
        unsigned short* nxt = (q & 1) ? bufA : bufB;
        if (q < 3) stage1g(ch + 1, nxt);     // loads issue early, hide under MFMA
#pragma unroll
        for (int tap = 0; tap < 9; ++tap) {
            int th = tap / 3, tw = tap % 3;
            bf16x8 bfr = *reinterpret_cast<const bf16x8*>(
                &cur[(th * 34 + p + tw) * XP1 + lq * 8]);
            bf16x8 af = wOmV[(((tap * 8 + ch) * 4 + lq) * 32) + mfp * 16 + lm];
            accOm = __builtin_amdgcn_mfma_f32_16x16x32_bf16(af, bfr, accOm, 0, 0, 0);
        }
        __syncthreads();
    }

    // group 1 deposits its partial (each (o,p) written exactly once)
    if (grp == 1) {
#pragma unroll
        for (int r = 0; r < 4; ++r) {
            int o = mfp * 16 + lq * 4 + r;
            if (o < 32)
                som_tmp[o * 32 + p] = accOm[r];
        }
    }
    __syncthreads();
    if (grp == 0) {
#pragma unroll
        for (int r = 0; r < 4; ++r) {
            int o = mfp * 16 + lq * 4 + r;
            if (o < OMC)
                om[((size_t)(b * OMC + o) * HH + h) * WW + w0 + p] =
                    accOm[r] + som_tmp[o * 32 + p] + b_om[o];
        }
    }
}

// ---------------------------------------------------------------------------
// Kernel B: deform gather + bf16 MFMA GEMM (R21-verified: 106.5us, MfmaUtil
// 15.0). 512 thr (8 waves), M=256, N=32, LDS 40KB -> 4 blocks/CU.
// TPW=17 b32 corner reads (R22's b64 variant regressed: lost gather MLP).
// XCD swizzle: obid=((raw&7)<<7)|(raw>>3) -> batch b on XCD b.
// ---------------------------------------------------------------------------
__global__ __launch_bounds__(512, 4) void deform_mfma_kernel(
    const float* __restrict__ x, const float* __restrict__ om,
    const unsigned short* __restrict__ wA, const float* __restrict__ b_dc,
    float* __restrict__ out)
{
    const int rawb = blockIdx.x;
    const int obid = ((rawb & 7) << 7) | (rawb >> 3);   // batch-per-XCD swizzle
    const int b    = obid >> 7;
    const int h    = (obid >> 1) & 63;
    const int w0   = (obid & 1) * NPIX;
    const int t    = threadIdx.x;
    const int wv   = t >> 6;             // wave 0..7
    const int lane = t & 63;
    const int lq   = lane >> 4;          // k-quarter
    const int lm   = lane & 15;

    __shared__ __align__(16) unsigned short sS[NPIX * SPITCH]; // 18944 B
    __shared__ __align__(16) unsigned short sR[8224];          // 16448 B tile
    __shared__ __align__(16) int4 s_par[9 * NPIX];             // 4608 B params

    const size_t xb_base = (size_t)b * CIN * HW;
    const float* gx_base = x + xb_base;

    // ---- staging precompute: entry n = t+i*512 over 3200 (rc,slot) ----
    // packed: lword(12b) | slot(4b)<<12 | goff(12b)<<16 ; -1 = inactive
    int stg[7];
#pragma unroll
    for (int i = 0; i < 7; ++i) {
        int n = t + i * 512;
        if (n < 3200) {
            int slot = n / 200;              // 0..15 (channel pair)
            int rc   = n - slot * 200;       // 0..199 (r*40+c)
            int r    = rc / 40;
            int c    = rc - r * 40;
            int gy   = min(max(h - 2 + r, 0), HH - 1);
            int gx   = min(max(w0 - 4 + c, 0), WW - 1);
            stg[i] = (rc * TPW + slot) | (slot << 12) | ((gy * WW + gx) << 16);
        } else stg[i] = -1;
    }

    unsigned int* tWw = reinterpret_cast<unsigned int*>(sR);
    const unsigned int* tW = tWw;

    // ---- prologue: issue chunk-0 staging loads, guard, params, write tile ----
    float L0[7], L1[7];
    {
        const float* gch = gx_base;
#pragma unroll
        for (int i = 0; i < 7; ++i)
            if (stg[i] >= 0) {
                int sl = (stg[i] >> 12) & 0xF;
                int go = (stg[i] >> 16) & 0xFFF;
                L0[i] = gch[(size_t)(2 * sl) * HW + go];
                L1[i] = gch[(size_t)(2 * sl + 1) * HW + go];
            }
    }

    // zero guard words [3400, 4112): read by weight-0 folded corners, never
    // staged; stale LDS could decode as bf16 NaN -> 0*NaN=NaN (R10 lesson).
    for (int i = t; i < 712; i += 512) tWw[3400 + i] = 0u;

    if (t < 9 * NPIX) {
        int tap = t >> 5;
        int pix = t & 31;
        const float* omb = om + ((size_t)b * OMC * HH + h) * WW + w0 + pix;
        float dy = omb[(size_t)(2 * tap) * HW];
        float dx = omb[(size_t)(2 * tap + 1) * HW];
        float mv = omb[(size_t)(18 + tap) * HW];
        float m  = 1.f / (1.f + expf(-mv));
        float py = (float)(h - 1 + tap / 3) + dy;
        float px = (float)(w0 + pix - 1 + tap % 3) + dx;
        float y0f = floorf(py), x0f = floorf(px);
        float wy1 = py - y0f, wx1 = px - x0f;
        float wy0 = 1.f - wy1, wx0 = 1.f - wx1;
        int y0 = (int)y0f, x0 = (int)x0f;
        int y1 = y0 + 1, x1 = x0 + 1;
        bool yv0 = (y0 >= 0) && (y0 < HH);
        bool yv1 = (y1 >= 0) && (y1 < HH);
        bool xv0 = (x0 >= 0) && (x0 < WW);
        bool xv1 = (x1 >= 0) && (x1 < WW);
        int yc0 = min(max(y0, 0), HH - 1), yc1 = min(max(y1, 0), HH - 1);
        int xc0 = min(max(x0, 0), WW - 1), xc1 = min(max(x1, 0), WW - 1);
        float wwx = (yv0 && xv0) ? wy0 * wx0 * m : 0.f;
        float wwy = (yv0 && xv1) ? wy0 * wx1 * m : 0.f;
        float wwz = (yv1 && xv0) ? wy1 * wx0 * m : 0.f;
        float www = (yv1 && xv1) ? wy1 * wx1 * m : 0.f;
        // fold clamp-duplicate corners into weights (exact: duplicated coord)
        if (xc1 == xc0) { wwx += wwy; wwy = 0.f; wwz += www; www = 0.f; }
        if (yc1 == yc0) { wwx += wwz; wwz = 0.f; wwy += www; www = 0.f; }
        bool inT = (yc0 >= h - 2) && (yc1 <= h + 2) &&
                   (xc0 >= w0 - 4) && (xc1 <= w0 + 35);
        int lb = (yc0 - (h - 2)) * 40 + (xc0 - (w0 - 4));
        int pk = (lb & 0xFF) | ((xc1 - xc0) << 8) | ((yc1 - yc0) << 9)
               | ((yc0 * WW + xc0) << 10);
        if (!inT) pk |= (int)0x80000000;
        __half2 wab = __floats2half2_rn(wwx, wwy);
        __half2 wcd = __floats2half2_rn(wwz, www);
        s_par[t] = make_int4(pk,
                             *reinterpret_cast<int*>(&wab),
                             *reinterpret_cast<int*>(&wcd), 0);
    }
    {   // write chunk-0 tile (waits staged loads)
#pragma unroll
        for (int i = 0; i < 7; ++i)
            if (stg[i] >= 0)
                tWw[stg[i] & 0xFFF] = pk2bf(L0[i], L1[i]);
    }
    __syncthreads();           // params + chunk-0 tile + guard ready

    // ================= main deform GEMM =================
    f32x4 acc[2][2];
#pragma unroll
    for (int i = 0; i < 2; ++i)
#pragma unroll
        for (int j = 0; j < 2; ++j)
            acc[i][j] = (f32x4)(0.f);

    const int pix  = t >> 4;             // 0..31 gather pixel
    const int slot = t & 15;             // 0..15 channel-pair slot

    for (int ch = 0; ch < 8; ++ch) {
        // ---- gather: 1 b128 param broadcast + 4 packed b32 corners per tap ----
#pragma unroll 3
        for (int tap = 0; tap < 9; ++tap) {
            int idx = tap * NPIX + pix;
            int4 pv = s_par[idx];
            int pk  = pv.x;
            float2 wab = __half22float2(*reinterpret_cast<__half2*>(&pv.y));
            float2 wcd = __half22float2(*reinterpret_cast<__half2*>(&pv.z));
            float v0, v1;
            if (pk >= 0) {
                int base = (pk & 0xFF) * TPW + slot;
                unsigned int a00 = tW[base];
                unsigned int a01 = tW[base + TPW];
                unsigned int a10 = tW[base + 40 * TPW];
                unsigned int a11 = tW[base + 41 * TPW];
                v0 = wab.x * bflo(a00) + wab.y * bflo(a01)
                   + wcd.x * bflo(a10) + wcd.y * bflo(a11);
                v1 = wab.x * bfhi(a00) + wab.y * bfhi(a01)
                   + wcd.x * bfhi(a10) + wcd.y * bfhi(a11);
            } else {
                int off00 = (pk >> 10) & 0xFFF;
                int d01 = (pk >> 8) & 1;
                int d10 = ((pk >> 9) & 1) * WW;
                const float* xc = x + xb_base + (size_t)(ch * 32 + 2 * slot) * HW;
                v0 = wab.x * xc[off00]       + wab.y * xc[off00 + d01]
                   + wcd.x * xc[off00 + d10] + wcd.y * xc[off00 + d10 + d01];
                xc += HW;
                v1 = wab.x * xc[off00]       + wab.y * xc[off00 + d01]
                   + wcd.x * xc[off00 + d10] + wcd.y * xc[off00 + d10 + d01];
            }
            *reinterpret_cast<unsigned int*>(
                &sS[pix * SPITCH + tap * 32 + 2 * slot]) = pk2bf(v0, v1);
        }
        __syncthreads();                  // sS ready; tile consumed

        // ---- issue next chunk's staging loads (hide under MFMA) ----
        if (ch < 7) {
            const float* gch = gx_base + (size_t)(ch + 1) * 32 * HW;
#pragma unroll
            for (int i = 0; i < 7; ++i)
                if (stg[i] >= 0) {
                    int sl = (stg[i] >> 12) & 0xF;
                    int go = (stg[i] >> 16) & 0xFFF;
                    L0[i] = gch[(size_t)(2 * sl) * HW + go];
                    L1[i] = gch[(size_t)(2 * sl + 1) * HW + go];
                }
        }

        // ---- MFMA: wave wv computes o in [wv*32, wv*32+32) ----
        const int kb_base = ch * 36;
        const bf16x8* wAv = reinterpret_cast<const bf16x8*>(wA);
#pragma unroll 1
        for (int ks = 0; ks < 9; ++ks) {
            bf16x8 bfr[2];
#pragma unroll
            for (int nf = 0; nf < 2; ++nf)
                bfr[nf] = *reinterpret_cast<const bf16x8*>(
                    &sS[(nf * 16 + lm) * SPITCH + ks * 32 + lq * 8]);
#pragma unroll
            for (int mf = 0; mf < 2; ++mf) {
                int o  = wv * 32 + mf * 16 + lm;
                int kb = kb_base + ks * 4 + lq;
                bf16x8 af = wAv[(size_t)kb * 256 + o];
#pragma unroll
                for (int nf = 0; nf < 2; ++nf)
                    acc[mf][nf] = __builtin_amdgcn_mfma_f32_16x16x32_bf16(
                        af, bfr[nf], acc[mf][nf], 0, 0, 0);
            }
        }

        // ---- write next tile (loads have landed under MFMA) ----
        if (ch < 7) {
#pragma unroll
            for (int i = 0; i < 7; ++i)
                if (stg[i] >= 0)
                    tWw[stg[i] & 0xFFF] = pk2bf(L0[i], L1[i]);
        }
        __syncthreads();        // sS free + next tile ready
    }

    // ---- epilogue: D row = lq*4 + r, col = lm ----
#pragma unroll
    for (int mf = 0; mf < 2; ++mf) {
#pragma unroll
        for (int r = 0; r < 4; ++r) {
            int o = wv * 32 + mf * 16 + lq * 4 + r;
            float bo = b_dc[o];
#pragma unroll
            for (int nf = 0; nf < 2; ++nf) {
                int p = nf * 16 + lm;
                out[((size_t)(b * 256 + o)) * HW + h * WW + w0 + p] = acc[mf][nf][r] + bo;
            }
        }
    }
}

extern "C" void kernel_launch(void* const* d_in, const int* in_sizes, int n_in,
                              void* d_out, int out_size, void* d_ws, size_t ws_size,
                              hipStream_t stream) {
    const float* x    = (const float*)d_in[0];
    const float* w_om = (const float*)d_in[1];
    const float* b_om = (const float*)d_in[2];
    const float* w_dc = (const float*)d_in[3];
    const float* b_dc = (const float*)d_in[4];
    float* out = (float*)d_out;

    unsigned short* wA   = (unsigned short*)d_ws;                    // 1,179,648 B
    unsigned short* wOmA = (unsigned short*)((char*)d_ws + 1179648); //   147,456 B
    float*          om   = (float*)((char*)d_ws + 1327104);          // 3,538,944 B

    prep_kernel<<<2304 + 288, 256, 0, stream>>>(w_dc, w_om, wA, wOmA);
    om_mfma_kernel<<<BB * HH * 2, 512, 0, stream>>>(x, wOmA, b_om, om);
    deform_mfma_kernel<<<BB * HH * 2, 512, 0, stream>>>(x, om, wA, b_dc, out);
}